// Round 3
// baseline (5966.566 us; speedup 1.0000x reference)
//
#include <hip/hip_runtime.h>

// GRU decoder, B=256, H=512, T=512.
// 16 batch-groups x 16 member-WGs = 256 WGs (1/CU). Group g = blockIdx&15 so
// all 16 members of a group share an XCD (bid%8 == g%8 under round-robin
// dispatch) -> h exchange + flag barrier stay in one XCD's L2. Member m owns
// h-outputs [m*32, m*32+32) -> 96 rows of W_hh resident in VGPRs as bf16 MFMA
// A-frags. Per step: mfma(W, h_hi)+mfma(W, h_lo), f32 gates, export h bf16
// hi/lo (double-buffered by t&1), 16-WG flag barrier (agent scope), reload.
// Barrier spin is BOUNDED: on timeout sets a global abort flag -> all blocks
// exit (wrong output, but a diagnosable failure instead of a dead container).
// [Round 3 = round 1 resubmitted verbatim: rounds 1-2 died on a dead
// container before the source was ever transmitted.]

typedef __attribute__((ext_vector_type(8))) short short8;
typedef __attribute__((ext_vector_type(4))) float f32x4;
typedef unsigned short ushort_t;
typedef unsigned int uint_t;

#define NG 16   // batch groups
#define NM 16   // members per group
#define NB 16   // batch rows per group
#define NJ 32   // h outputs per member
#define TPB 384 // 6 waves; waves 0..2 do MFMA (2 row-tiles each)
#define BUFE (256 * 512) // elements per h buffer
#define SPIN_MAX (1u << 22)

__device__ __forceinline__ ushort_t bf16_rne(float f) {
  uint_t u = __float_as_uint(f);
  return (ushort_t)((u + 0x7fffu + ((u >> 16) & 1u)) >> 16);
}
__device__ __forceinline__ float bf16f(ushort_t h) {
  return __uint_as_float(((uint_t)h) << 16);
}
// slab row (0..95) -> global gate row in [0,1536)
__device__ __forceinline__ int gRow(int rs, int m) {
  int base = m * NJ;
  if (rs < 32) return base + rs;
  if (rs < 64) return 512 + base + (rs - 32);
  return 1024 + base + (rs - 64);
}

// Load one 16-row x 512-col tile of W (f32) into 16 bf16 A-frags.
// A-frag (16x16x32 bf16): lane holds A[row=lane&15][k=(lane>>4)*8+i].
template <bool LO>
__device__ __forceinline__ void loadW(short8* dst, const float* __restrict__ W,
                                      int tile, int m, int lane) {
  int rs = tile * 16 + (lane & 15);
  const float* p = W + (size_t)gRow(rs, m) * 512 + ((lane >> 4) << 3);
#pragma unroll
  for (int c = 0; c < 16; ++c) {
    const float* pc = p + c * 32;
    short8 o;
#pragma unroll
    for (int i = 0; i < 8; ++i) {
      float v = pc[i];
      ushort_t hi = bf16_rne(v);
      o[i] = LO ? (short)bf16_rne(v - bf16f(hi)) : (short)hi;
    }
    dst[c] = o;
  }
}

__global__ __launch_bounds__(TPB, 1) void gru_kernel(
    const float* __restrict__ x, const float* __restrict__ Wih,
    const float* __restrict__ Whh, const float* __restrict__ bih,
    const float* __restrict__ bhh, float* __restrict__ out,
    ushort_t* __restrict__ gbuf, uint_t* __restrict__ cnt, int NT) {
  __shared__ __align__(16) char s_hhi[NB * 1024]; // h bf16-hi, XOR-swizzled
  __shared__ __align__(16) char s_hlo[NB * 1024]; // h bf16-lo
  __shared__ float s_gi[96 * 17];
  __shared__ float s_gh[96 * 17];
  __shared__ float s_hloc[NB * NJ]; // own h slice, f32 across steps
  __shared__ float s_bhh[NJ];       // b_hh n-rows
  __shared__ int s_stop;

  const int tid = threadIdx.x;
  const int lane = tid & 63;
  const int w = tid >> 6;
  const int bid = blockIdx.x;
  const int g = bid & 15;  // batch group (same XCD for all members)
  const int m = bid >> 4;  // member
  if (NT <= 0) return;

  // ---- stage relu(x) as bf16 hi/lo into swizzled LDS ----
  for (int i = tid; i < NB * 64; i += TPB) {
    int b = i >> 6, k0 = (i & 63) << 3;
    const float* px = x + (size_t)(g * NB + b) * 512 + k0;
    short8 vh, vl;
#pragma unroll
    for (int ii = 0; ii < 8; ++ii) {
      float xv = px[ii];
      xv = xv > 0.f ? xv : 0.f;
      ushort_t hb = bf16_rne(xv);
      vh[ii] = (short)hb;
      vl[ii] = (short)bf16_rne(xv - bf16f(hb));
    }
    int off = ((b << 10) + (k0 << 1)) ^ ((b & 7) << 4);
    *(short8*)(s_hhi + off) = vh;
    *(short8*)(s_hlo + off) = vl;
  }
  if (tid < NJ) s_bhh[tid] = bhh[1024 + m * NJ + tid];
  if (tid == 0) s_stop = 0;
  __syncthreads();

  short8 wA[16], wB[16];
  const f32x4 vzero = {0.f, 0.f, 0.f, 0.f};
  f32x4 acc0 = vzero, acc1 = vzero;
  const int bcol = lane & 15;
  const int swzb = (bcol & 7) << 4;
  const int kb0 = (lane >> 4) << 4;

  // ---- gi = relu(x) @ W_ih^T (3-term hi/lo split) ----
  if (w < 3) {
    loadW<false>(wA, Wih, 2 * w, m, lane);
    loadW<false>(wB, Wih, 2 * w + 1, m, lane);
#pragma unroll
    for (int c = 0; c < 16; ++c) {
      int off = ((bcol << 10) + (c << 6) + kb0) ^ swzb;
      short8 bh = *(const short8*)(s_hhi + off);
      short8 bl = *(const short8*)(s_hlo + off);
      acc0 = __builtin_amdgcn_mfma_f32_16x16x32_bf16(wA[c], bh, acc0, 0, 0, 0);
      acc0 = __builtin_amdgcn_mfma_f32_16x16x32_bf16(wA[c], bl, acc0, 0, 0, 0);
      acc1 = __builtin_amdgcn_mfma_f32_16x16x32_bf16(wB[c], bh, acc1, 0, 0, 0);
      acc1 = __builtin_amdgcn_mfma_f32_16x16x32_bf16(wB[c], bl, acc1, 0, 0, 0);
    }
    loadW<true>(wA, Wih, 2 * w, m, lane);
    loadW<true>(wB, Wih, 2 * w + 1, m, lane);
#pragma unroll
    for (int c = 0; c < 16; ++c) {
      int off = ((bcol << 10) + (c << 6) + kb0) ^ swzb;
      short8 bh = *(const short8*)(s_hhi + off);
      acc0 = __builtin_amdgcn_mfma_f32_16x16x32_bf16(wA[c], bh, acc0, 0, 0, 0);
      acc1 = __builtin_amdgcn_mfma_f32_16x16x32_bf16(wB[c], bh, acc1, 0, 0, 0);
    }
  }
  __syncthreads();
  if (w < 3) {
    int drow = (lane >> 4) << 2;
#pragma unroll
    for (int q = 0; q < 4; ++q) {
      int rs0 = 2 * w * 16 + drow + q, rs1 = rs0 + 16;
      int g0 = gRow(rs0, m), g1 = gRow(rs1, m);
      s_gi[rs0 * 17 + bcol] = acc0[q] + bih[g0] + (rs0 < 64 ? bhh[g0] : 0.f);
      s_gi[rs1 * 17 + bcol] = acc1[q] + bih[g1] + (rs1 < 64 ? bhh[g1] : 0.f);
    }
    loadW<false>(wA, Whh, 2 * w, m, lane); // W_hh resident from here
    loadW<false>(wB, Whh, 2 * w + 1, m, lane);
  }
  for (int i = tid; i < 4096; i += TPB) { // h0 = 0
    ((int*)s_hhi)[i] = 0;
    ((int*)s_hlo)[i] = 0;
  }
  for (int i = tid; i < NB * NJ; i += TPB) s_hloc[i] = 0.f;
  __syncthreads();

  const size_t outRow = (size_t)NT * 512;
  float* outBase = out + (size_t)(g * NB) * outRow + m * NJ;

  for (int t = 0; t < NT; ++t) {
    if (w < 3) {
      acc0 = vzero;
      acc1 = vzero;
#pragma unroll
      for (int c = 0; c < 16; ++c) {
        int off = ((bcol << 10) + (c << 6) + kb0) ^ swzb;
        short8 bh = *(const short8*)(s_hhi + off);
        short8 bl = *(const short8*)(s_hlo + off);
        acc0 = __builtin_amdgcn_mfma_f32_16x16x32_bf16(wA[c], bh, acc0, 0, 0, 0);
        acc0 = __builtin_amdgcn_mfma_f32_16x16x32_bf16(wA[c], bl, acc0, 0, 0, 0);
        acc1 = __builtin_amdgcn_mfma_f32_16x16x32_bf16(wB[c], bh, acc1, 0, 0, 0);
        acc1 = __builtin_amdgcn_mfma_f32_16x16x32_bf16(wB[c], bl, acc1, 0, 0, 0);
      }
      int drow = (lane >> 4) << 2;
#pragma unroll
      for (int q = 0; q < 4; ++q) {
        s_gh[(2 * w * 16 + drow + q) * 17 + bcol] = acc0[q];
        s_gh[((2 * w + 1) * 16 + drow + q) * 17 + bcol] = acc1[q];
      }
    }
    __syncthreads();
    ushort_t* ghiW = gbuf + (size_t)(t & 1) * 2 * BUFE;
    ushort_t* gloW = ghiW + BUFE;
    for (int idx = tid; idx < NB * NJ; idx += TPB) {
      int b = idx >> 5, j = idx & 31;
      float pr = s_gi[j * 17 + b] + s_gh[j * 17 + b];
      float pz = s_gi[(32 + j) * 17 + b] + s_gh[(32 + j) * 17 + b];
      float r = 1.f / (1.f + __expf(-pr));
      float z = 1.f / (1.f + __expf(-pz));
      float pn = s_gi[(64 + j) * 17 + b] + r * (s_gh[(64 + j) * 17 + b] + s_bhh[j]);
      float n = 1.f - 2.f / (1.f + __expf(2.f * pn));
      float hn = n + z * (s_hloc[idx] - n);
      s_hloc[idx] = hn;
      __builtin_nontemporal_store(hn, outBase + (size_t)b * outRow + (size_t)t * 512 + j);
      ushort_t hb = bf16_rne(hn);
      int gidx = (g * NB + b) * 512 + m * NJ + j;
      ghiW[gidx] = hb;
      gloW[gidx] = bf16_rne(hn - bf16f(hb));
    }
    __syncthreads(); // drains vmcnt per wave before the release flag
    if (tid == 0) {
      __hip_atomic_fetch_add(&cnt[g], 1u, __ATOMIC_RELEASE,
                             __HIP_MEMORY_SCOPE_AGENT);
      uint_t tgt = (uint_t)NM * (uint_t)(t + 1);
      uint_t sp = 0;
      while (__hip_atomic_load(&cnt[g], __ATOMIC_ACQUIRE,
                               __HIP_MEMORY_SCOPE_AGENT) < tgt) {
        if (++sp > SPIN_MAX) { // deadlock: abort everyone, fail visibly
          __hip_atomic_store(&cnt[32], 1u, __ATOMIC_RELEASE,
                             __HIP_MEMORY_SCOPE_AGENT);
          s_stop = 1;
          break;
        }
        if ((sp & 2047u) == 0u &&
            __hip_atomic_load(&cnt[32], __ATOMIC_RELAXED,
                              __HIP_MEMORY_SCOPE_AGENT) != 0u) {
          s_stop = 1;
          break;
        }
      }
    }
    __syncthreads();
    if (s_stop) break;
    for (int i = tid; i < 2048; i += TPB) { // reload group h into LDS
      int sel = i >> 10, rr = i & 1023;
      int b = rr >> 6, k0 = (rr & 63) << 3;
      const ushort_t* src = (sel ? gloW : ghiW) + (size_t)(g * NB + b) * 512 + k0;
      char* dst = (sel ? s_hlo : s_hhi);
      *(short8*)(dst + (((b << 10) + (k0 << 1)) ^ ((b & 7) << 4))) =
          *(const short8*)src;
    }
    __syncthreads();
  }
}

extern "C" void kernel_launch(void* const* d_in, const int* in_sizes, int n_in,
                              void* d_out, int out_size, void* d_ws,
                              size_t ws_size, hipStream_t stream) {
  const float* x = (const float*)d_in[0];
  const float* Wih = (const float*)d_in[1];
  const float* Whh = (const float*)d_in[2];
  const float* bih = (const float*)d_in[3];
  const float* bhh = (const float*)d_in[4];
  float* out = (float*)d_out;
  int NT = out_size / (256 * 512); // robust: don't trust seq_len dtype
  // ws: [0,256) counters+abort, then 4 h-buffers (hi0,lo0,hi1,lo1) 256KB each
  uint_t* cnt = (uint_t*)d_ws;
  ushort_t* gbuf = (ushort_t*)((char*)d_ws + 256);
  hipMemsetAsync(d_ws, 0, 256, stream);
  hipLaunchKernelGGL(gru_kernel, dim3(NG * NM), dim3(TPB), 0, stream, x, Wih,
                     Whh, bih, bhh, out, gbuf, cnt, NT);
}

// Round 4
// 1408.051 us; speedup vs baseline: 4.2375x; 4.2375x over previous
//
#include <hip/hip_runtime.h>

// GRU decoder, B=256, H=512, T=512. 16 groups x 16 members = 256 WGs (1/CU).
// Member m holds 96 rows of W_hh in reg as bf16 MFMA A-frags. Per step:
// mfma(W, h_hi)+mfma(W, h_lo) -> gates f32 -> h exported as packed bf16
// hi|lo u32 via RELAXED agent atomics (sc1, no buffer_inv/wbl2!), per-member
// flag barrier (128B-spaced, single-writer, relaxed), batched u64 reload.
// Round-3 post-mortem: ACQUIRE polls emitted buffer_inv (L2 invalidate) per
// iteration and RELEASE RMWs emitted buffer_wbl2 -> 12us/step. This version
// has zero acquire/release fences; ordering = vmcnt-drain-then-flag.

typedef __attribute__((ext_vector_type(8))) short short8;
typedef __attribute__((ext_vector_type(4))) float f32x4;
typedef unsigned short ushort_t;
typedef unsigned int uint_t;
typedef unsigned long long u64_t;

#define NG 16
#define NM 16
#define NB 16
#define NJ 32
#define TPB 384
#define SPIN_MAX (1u << 16)
#define ABORT_IDX 8192          // u32 index in flags region (byte 32768)
#define GBUF_BASE 16384         // u32 index of data region (byte 65536)
#define GRP_U32 8192            // 16 members * 512 u32
#define BUF_U32 131072          // 16 groups * GRP_U32

__device__ __forceinline__ ushort_t bf16_rne(float f) {
  uint_t u = __float_as_uint(f);
  return (ushort_t)((u + 0x7fffu + ((u >> 16) & 1u)) >> 16);
}
__device__ __forceinline__ float bf16f(ushort_t h) {
  return __uint_as_float(((uint_t)h) << 16);
}
__device__ __forceinline__ int gRow(int rs, int m) {
  int base = m * NJ;
  if (rs < 32) return base + rs;
  if (rs < 64) return 512 + base + (rs - 32);
  return 1024 + base + (rs - 64);
}

template <bool LO>
__device__ __forceinline__ void loadW(short8* dst, const float* __restrict__ W,
                                      int tile, int m, int lane) {
  int rs = tile * 16 + (lane & 15);
  const float* p = W + (size_t)gRow(rs, m) * 512 + ((lane >> 4) << 3);
#pragma unroll
  for (int c = 0; c < 16; ++c) {
    const float* pc = p + c * 32;
    short8 o;
#pragma unroll
    for (int i = 0; i < 8; ++i) {
      float v = pc[i];
      ushort_t hi = bf16_rne(v);
      o[i] = LO ? (short)bf16_rne(v - bf16f(hi)) : (short)hi;
    }
    dst[c] = o;
  }
}

__global__ __launch_bounds__(TPB, 1) void gru_kernel(
    const float* __restrict__ x, const float* __restrict__ Wih,
    const float* __restrict__ Whh, const float* __restrict__ bih,
    const float* __restrict__ bhh, float* __restrict__ out,
    uint_t* __restrict__ wsp, int NT) {
  __shared__ __align__(16) char s_hhi[NB * 1024]; // h bf16-hi, XOR-swizzled
  __shared__ __align__(16) char s_hlo[NB * 1024]; // h bf16-lo
  __shared__ float s_gi[96 * 17];
  __shared__ float s_gh[96 * 17];
  __shared__ float s_hloc[NB * NJ];
  __shared__ float s_bhh[NJ];
  __shared__ int s_stop;

  const int tid = threadIdx.x;
  const int lane = tid & 63;
  const int w = tid >> 6;
  const int bid = blockIdx.x;
  const int g = bid & 15;
  const int m = bid >> 4;
  if (NT <= 0) return;

  uint_t* flags = wsp;
  uint_t* gbuf = wsp + GBUF_BASE;

  // ---- stage relu(x) as bf16 hi/lo into swizzled LDS ----
  for (int i = tid; i < NB * 64; i += TPB) {
    int b = i >> 6, k0 = (i & 63) << 3;
    const float* px = x + (size_t)(g * NB + b) * 512 + k0;
    short8 vh, vl;
#pragma unroll
    for (int ii = 0; ii < 8; ++ii) {
      float xv = px[ii];
      xv = xv > 0.f ? xv : 0.f;
      ushort_t hb = bf16_rne(xv);
      vh[ii] = (short)hb;
      vl[ii] = (short)bf16_rne(xv - bf16f(hb));
    }
    int off = ((b << 10) + (k0 << 1)) ^ ((b & 7) << 4);
    *(short8*)(s_hhi + off) = vh;
    *(short8*)(s_hlo + off) = vl;
  }
  if (tid < NJ) s_bhh[tid] = bhh[1024 + m * NJ + tid];
  if (tid == 0) s_stop = 0;
  __syncthreads();

  short8 wA[16], wB[16];
  const f32x4 vzero = {0.f, 0.f, 0.f, 0.f};
  f32x4 acc0 = vzero, acc1 = vzero;
  const int bcol = lane & 15;
  const int swzb = (bcol & 7) << 4;
  const int kb0 = (lane >> 4) << 4;

  // ---- gi = relu(x) @ W_ih^T (3-term hi/lo split) ----
  if (w < 3) {
    loadW<false>(wA, Wih, 2 * w, m, lane);
    loadW<false>(wB, Wih, 2 * w + 1, m, lane);
#pragma unroll
    for (int c = 0; c < 16; ++c) {
      int off = ((bcol << 10) + (c << 6) + kb0) ^ swzb;
      short8 bh = *(const short8*)(s_hhi + off);
      short8 bl = *(const short8*)(s_hlo + off);
      acc0 = __builtin_amdgcn_mfma_f32_16x16x32_bf16(wA[c], bh, acc0, 0, 0, 0);
      acc0 = __builtin_amdgcn_mfma_f32_16x16x32_bf16(wA[c], bl, acc0, 0, 0, 0);
      acc1 = __builtin_amdgcn_mfma_f32_16x16x32_bf16(wB[c], bh, acc1, 0, 0, 0);
      acc1 = __builtin_amdgcn_mfma_f32_16x16x32_bf16(wB[c], bl, acc1, 0, 0, 0);
    }
    loadW<true>(wA, Wih, 2 * w, m, lane);
    loadW<true>(wB, Wih, 2 * w + 1, m, lane);
#pragma unroll
    for (int c = 0; c < 16; ++c) {
      int off = ((bcol << 10) + (c << 6) + kb0) ^ swzb;
      short8 bh = *(const short8*)(s_hhi + off);
      acc0 = __builtin_amdgcn_mfma_f32_16x16x32_bf16(wA[c], bh, acc0, 0, 0, 0);
      acc1 = __builtin_amdgcn_mfma_f32_16x16x32_bf16(wB[c], bh, acc1, 0, 0, 0);
    }
  }
  __syncthreads();
  if (w < 3) {
    int drow = (lane >> 4) << 2;
#pragma unroll
    for (int q = 0; q < 4; ++q) {
      int rs0 = 2 * w * 16 + drow + q, rs1 = rs0 + 16;
      int g0 = gRow(rs0, m), g1 = gRow(rs1, m);
      s_gi[rs0 * 17 + bcol] = acc0[q] + bih[g0] + (rs0 < 64 ? bhh[g0] : 0.f);
      s_gi[rs1 * 17 + bcol] = acc1[q] + bih[g1] + (rs1 < 64 ? bhh[g1] : 0.f);
    }
    loadW<false>(wA, Whh, 2 * w, m, lane); // W_hh resident from here
    loadW<false>(wB, Whh, 2 * w + 1, m, lane);
  }
  for (int i = tid; i < 4096; i += TPB) { // h0 = 0
    ((int*)s_hhi)[i] = 0;
    ((int*)s_hlo)[i] = 0;
  }
  for (int i = tid; i < NB * NJ; i += TPB) s_hloc[i] = 0.f;
  __syncthreads();

  const size_t outRow = (size_t)NT * 512;
  float* outBase = out + (size_t)(g * NB) * outRow + m * NJ;

  for (int t = 0; t < NT; ++t) {
    // ---- 1: gh = W_hh @ h (hi + lo) ----
    if (w < 3) {
      acc0 = vzero;
      acc1 = vzero;
#pragma unroll
      for (int c = 0; c < 16; ++c) {
        int off = ((bcol << 10) + (c << 6) + kb0) ^ swzb;
        short8 bh = *(const short8*)(s_hhi + off);
        short8 bl = *(const short8*)(s_hlo + off);
        acc0 = __builtin_amdgcn_mfma_f32_16x16x32_bf16(wA[c], bh, acc0, 0, 0, 0);
        acc0 = __builtin_amdgcn_mfma_f32_16x16x32_bf16(wA[c], bl, acc0, 0, 0, 0);
        acc1 = __builtin_amdgcn_mfma_f32_16x16x32_bf16(wB[c], bh, acc1, 0, 0, 0);
        acc1 = __builtin_amdgcn_mfma_f32_16x16x32_bf16(wB[c], bl, acc1, 0, 0, 0);
      }
      int drow = (lane >> 4) << 2;
#pragma unroll
      for (int q = 0; q < 4; ++q) {
        s_gh[(2 * w * 16 + drow + q) * 17 + bcol] = acc0[q];
        s_gh[((2 * w + 1) * 16 + drow + q) * 17 + bcol] = acc1[q];
      }
    }
    __syncthreads();

    // ---- 2: gates (2 elems/thread, tid<256) + out + sc1 h-export ----
    u64_t* dstq = (u64_t*)(gbuf + (size_t)(t & 1) * BUF_U32 + g * GRP_U32 +
                           m * 512);
    if (tid < 256) {
      int b = tid >> 4, j0 = (tid & 15) << 1;
      float hn01[2];
#pragma unroll
      for (int e = 0; e < 2; ++e) {
        int j = j0 + e;
        float pr = s_gi[j * 17 + b] + s_gh[j * 17 + b];
        float pz = s_gi[(32 + j) * 17 + b] + s_gh[(32 + j) * 17 + b];
        float r = 1.f / (1.f + __expf(-pr));
        float z = 1.f / (1.f + __expf(-pz));
        float pn =
            s_gi[(64 + j) * 17 + b] + r * (s_gh[(64 + j) * 17 + b] + s_bhh[j]);
        float n = 1.f - 2.f / (1.f + __expf(2.f * pn));
        float hn = n + z * (s_hloc[b * 32 + j] - n);
        s_hloc[b * 32 + j] = hn;
        hn01[e] = hn;
      }
      float2 ov = {hn01[0], hn01[1]};
      *(float2*)(outBase + (size_t)b * outRow + (size_t)t * 512 + j0) = ov;
      ushort_t h0 = bf16_rne(hn01[0]);
      ushort_t h1 = bf16_rne(hn01[1]);
      uint_t p0 = (uint_t)h0 | ((uint_t)bf16_rne(hn01[0] - bf16f(h0)) << 16);
      uint_t p1 = (uint_t)h1 | ((uint_t)bf16_rne(hn01[1] - bf16f(h1)) << 16);
      u64_t pq = (u64_t)p0 | ((u64_t)p1 << 32);
      __hip_atomic_store(dstq + tid, pq, __ATOMIC_RELAXED,
                         __HIP_MEMORY_SCOPE_AGENT);
    }
    __syncthreads(); // drains vmcnt per wave: h-export globally visible

    // ---- 3: flag + poll (relaxed agent; no cache inv/wb) ----
    if (tid == 0)
      __hip_atomic_store(&flags[((g << 4) + m) << 5], (uint_t)(t + 1),
                         __ATOMIC_RELAXED, __HIP_MEMORY_SCOPE_AGENT);
    if (w == 0) {
      const uint_t tgt = (uint_t)(t + 1);
      uint_t* fp = flags + (((g << 4) + (lane & 15)) << 5);
      uint_t sp = 0;
      for (;;) {
        uint_t v = 0xffffffffu;
        if (lane < 16)
          v = __hip_atomic_load(fp, __ATOMIC_RELAXED, __HIP_MEMORY_SCOPE_AGENT);
        if (__all((int)(v >= tgt))) break;
        ++sp;
        uint_t ab = 0;
        if ((sp & 127u) == 0u) {
          ab = __hip_atomic_load(&flags[ABORT_IDX], __ATOMIC_RELAXED,
                                 __HIP_MEMORY_SCOPE_AGENT);
          if (sp > SPIN_MAX) {
            __hip_atomic_store(&flags[ABORT_IDX], 1u, __ATOMIC_RELAXED,
                               __HIP_MEMORY_SCOPE_AGENT);
            ab = 1;
          }
        }
        if (__any((int)(ab != 0))) {
          if (tid == 0) s_stop = 1;
          break;
        }
        __builtin_amdgcn_s_sleep(1);
      }
    }
    __syncthreads();
    if (s_stop) break;

    // ---- 4: reload group h (batched relaxed u64 loads -> pipelined) ----
    {
      const u64_t* srcq =
          (const u64_t*)(gbuf + (size_t)(t & 1) * BUF_U32 + g * GRP_U32);
#define LDI(k)                                                                 \
  __hip_atomic_load(srcq + (tid + (k) * TPB), __ATOMIC_RELAXED,                \
                    __HIP_MEMORY_SCOPE_AGENT)
      u64_t q0 = LDI(0), q1 = LDI(1), q2 = LDI(2), q3 = LDI(3), q4 = LDI(4);
      u64_t q5 = LDI(5), q6 = LDI(6), q7 = LDI(7), q8 = LDI(8), q9 = LDI(9);
      u64_t q10 = (tid < 256) ? LDI(10) : 0ull;
#undef LDI
#define UNP(k, qq)                                                             \
  {                                                                            \
    int i = tid + (k) * TPB;                                                   \
    int mcol = ((i >> 8) << 5) + ((i & 15) << 1);                              \
    int b = (i >> 4) & 15;                                                     \
    int off = ((b << 10) + (mcol << 1)) ^ ((b & 7) << 4);                      \
    uint_t w0 = (uint_t)(qq), w1 = (uint_t)((qq) >> 32);                       \
    *(uint_t*)(s_hhi + off) = (w0 & 0xffffu) | ((w1 & 0xffffu) << 16);         \
    *(uint_t*)(s_hlo + off) = (w0 >> 16) | (w1 & 0xffff0000u);                 \
  }
      UNP(0, q0) UNP(1, q1) UNP(2, q2) UNP(3, q3) UNP(4, q4) UNP(5, q5)
      UNP(6, q6) UNP(7, q7) UNP(8, q8) UNP(9, q9)
      if (tid < 256) UNP(10, q10)
#undef UNP
    }
    __syncthreads();
  }
}

extern "C" void kernel_launch(void* const* d_in, const int* in_sizes, int n_in,
                              void* d_out, int out_size, void* d_ws,
                              size_t ws_size, hipStream_t stream) {
  const float* x = (const float*)d_in[0];
  const float* Wih = (const float*)d_in[1];
  const float* Whh = (const float*)d_in[2];
  const float* bih = (const float*)d_in[3];
  const float* bhh = (const float*)d_in[4];
  float* out = (float*)d_out;
  int NT = out_size / (256 * 512);
  // ws: [0,32KB) flags (128B-spaced) + abort @32KB; data @64KB: 2 x 512KB
  uint_t* wsp = (uint_t*)d_ws;
  hipMemsetAsync(d_ws, 0, 65536, stream);
  hipLaunchKernelGGL(gru_kernel, dim3(NG * NM), dim3(TPB), 0, stream, x, Wih,
                     Whh, bih, bhh, out, wsp, NT);
}